// Round 1
// baseline (1697.259 us; speedup 1.0000x reference)
//
#include <hip/hip_runtime.h>

#define B_   32
#define C_   128
#define L_   4096
#define FL_  9
#define DIM_ 512
#define BCL  ((size_t)B_ * C_ * L_)
#define LT   32

__device__ __forceinline__ float gelu_f(float x) {
    return 0.5f * x * (1.0f + erff(x * 0.70710678118654752440f));
}
__device__ __forceinline__ float sigm_f(float x) {
    return 1.0f / (1.0f + expf(-x));
}

__device__ __forceinline__ float block_sum_256(float v, float* red) {
    #pragma unroll
    for (int off = 32; off > 0; off >>= 1) v += __shfl_down(v, off);
    const int wv = threadIdx.x >> 6, ln = threadIdx.x & 63;
    if (ln == 0) red[wv] = v;
    __syncthreads();
    return red[0] + red[1] + red[2] + red[3];
}

// ---------------- mean over L (level 0 feat) ----------------
__global__ __launch_bounds__(256) void mean_kernel(const float* __restrict__ in,
                                                   float* __restrict__ feat_sum) {
    __shared__ float red[4];
    const int bc = blockIdx.x;
    const int t = threadIdx.x;
    const size_t base = (size_t)bc * L_;
    float v = 0.f;
    for (int j = t; j < L_; j += 256) v += in[base + j];
    float tot = block_sum_256(v, red);
    if (t == 0) feat_sum[bc] = tot;
}

// ---------------- filter MLP (per level) ----------------
__global__ __launch_bounds__(1024) void mlp_kernel(
    const float* __restrict__ feat_sum,
    const float* __restrict__ stat_w, const float* __restrict__ stat_b,
    const float* __restrict__ wg1_w,  const float* __restrict__ wg1_b,
    const float* __restrict__ wg2_w,  const float* __restrict__ wg2_b,
    float* __restrict__ lo_out, float* __restrict__ hi_out) {
    __shared__ float fs[C_];
    __shared__ float h1[DIM_];
    __shared__ float h2[2 * DIM_];
    const int b = blockIdx.x, t = threadIdx.x;
    if (t < C_) fs[t] = feat_sum[b * C_ + t] * (1.0f / (float)L_);
    __syncthreads();
    if (t < DIM_) {
        float acc = stat_b[t];
        const float* w = stat_w + (size_t)t * C_;
        for (int i = 0; i < C_; i++) acc += w[i] * fs[i];
        h1[t] = gelu_f(acc);
    }
    __syncthreads();
    {
        float acc = wg1_b[t];
        const float* w = wg1_w + (size_t)t * DIM_;
        for (int i = 0; i < DIM_; i++) acc += w[i] * h1[i];
        h2[t] = gelu_f(acc);
    }
    __syncthreads();
    if (t < 2 * FL_) {
        float acc = wg2_b[t];
        const float* w = wg2_w + (size_t)t * 2 * DIM_;
        for (int i = 0; i < 2 * DIM_; i++) acc += w[i] * h2[i];
        if (t < FL_) lo_out[b * FL_ + t] = acc;
        else         hi_out[b * FL_ + (t - FL_)] = acc;
    }
}

// ---------------- per-sample depthwise 9-tap conv (edge pad), fused feat for next level ----------------
__global__ __launch_bounds__(256) void dwconv_kernel(
    const float* __restrict__ in, const float* __restrict__ lo_f, const float* __restrict__ hi_f,
    float* __restrict__ out_lo, float* __restrict__ out_hi, float* __restrict__ feat_next) {
    __shared__ float s[256 + 8];
    __shared__ float red[4];
    const int t = threadIdx.x;
    const int l0 = blockIdx.x * 256;
    const int c = blockIdx.y;
    const int b = blockIdx.z;
    const size_t base = ((size_t)b * C_ + c) * L_;
    int g = l0 + t - 4;
    g = min(max(g, 0), L_ - 1);
    s[t] = in[base + g];
    if (t < 8) {
        int g2 = min(l0 + 256 + t - 4, L_ - 1);
        s[256 + t] = in[base + g2];
    }
    float lo[FL_], hi[FL_];
    #pragma unroll
    for (int k = 0; k < FL_; k++) { lo[k] = lo_f[b * FL_ + k]; hi[k] = hi_f[b * FL_ + k]; }
    __syncthreads();
    float aL = 0.f, aH = 0.f;
    #pragma unroll
    for (int k = 0; k < FL_; k++) { float v = s[t + k]; aL += lo[k] * v; aH += hi[k] * v; }
    out_lo[base + l0 + t] = aL;
    out_hi[base + l0 + t] = aH;
    if (feat_next) {
        float tot = block_sum_256(aL, red);
        if (t == 0) atomicAdd(&feat_next[b * C_ + c], tot);
    }
}

// ---------------- ortho + energy scalars (last level's lo_f) ----------------
__global__ void ortho_kernel(const float* __restrict__ lo2, float* __restrict__ scal) {
    const int t = threadIdx.x;
    float smooth = 0.f, sabs2 = 0.f, amp = 0.f;
    if (t < B_) {
        const float* lo = lo2 + t * FL_;
        float ss = 0.f, sa = 0.f, sm = 0.f, prev = 0.f;
        #pragma unroll
        for (int k = 0; k < FL_; k++) {
            float v = lo[k];
            sm += fabsf(v - prev);
            prev = v;
            ss += v * v;
            sa += fabsf(v);
        }
        sm += fabsf(prev);
        float den = sqrtf(ss) + 1e-8f;
        float san = sa / den;
        sabs2 = san * san;
        amp = fabsf(ss / (den * den) - 1.0f);
        smooth = sm;
    }
    #pragma unroll
    for (int off = 32; off > 0; off >>= 1) {
        smooth += __shfl_down(smooth, off);
        sabs2  += __shfl_down(sabs2, off);
        amp    += __shfl_down(amp, off);
    }
    if (t == 0) {
        float lo_smooth = smooth / (float)(B_ * 10);
        float shift = 3.0f * (sabs2 / (float)B_) / 81.0f;  // mean|outer| = (sum|a|)^2/81, x3 shifts
        float ortho = 0.01f * (shift + amp / (float)B_) + 0.1f * lo_smooth;
        scal[0] = ortho;
        scal[1] = 0.0f;  // energy_loss: dx_dt == 0 exactly
    }
}

// ---------------- fused reconstruction step: [attn ->] detail' -> gate conv -> current update ----------------
template <bool HAS_ATTN>
__global__ __launch_bounds__(256) void recon_kernel(
    const float* __restrict__ cur_in, const float* __restrict__ det_in,
    float* __restrict__ det_out, float* __restrict__ cur_out,
    const float* __restrict__ gw, const float* __restrict__ gb,
    const float* __restrict__ w1, const float* __restrict__ b1,
    const float* __restrict__ w2, const float* __restrict__ b2) {
    __shared__ float cur_s[C_ * 36];  // 128 rows, 34 valid cols, stride 36 (16B-aligned rows)
    __shared__ float a_s[32 * 36];
    const int t = threadIdx.x;
    const int b = blockIdx.y;
    const int l0 = blockIdx.x * LT;
    const float* curb = cur_in + (size_t)b * C_ * L_;

    // phase 1: stage current tile (zero pad at sequence edges)
    for (int i = t; i < C_ * 34; i += 256) {
        int ci = i / 34;
        int lo = i - ci * 34;
        int gl = l0 - 1 + lo;
        float v = (gl >= 0 && gl < L_) ? curb[(size_t)ci * L_ + gl] : 0.0f;
        cur_s[ci * 36 + lo] = v;
    }
    __syncthreads();

    const int c = t >> 1, half = t & 1, lb = 16 * half;
    float dpv[16];

    if (HAS_ATTN) {
        {   // phase 2: a = gelu(1x1 conv C->32)
            const int c4 = t >> 3, lsub = t & 7;
            float acc[4];
            float bb = b1[c4];
            #pragma unroll
            for (int k = 0; k < 4; k++) acc[k] = bb;
            const float* w1r = w1 + c4 * C_;
            for (int ci = 0; ci < C_; ci++) {
                float w = w1r[ci];
                #pragma unroll
                for (int k = 0; k < 4; k++) acc[k] += w * cur_s[ci * 36 + 1 + lsub + 8 * k];
            }
            #pragma unroll
            for (int k = 0; k < 4; k++) a_s[c4 * 36 + lsub + 8 * k] = gelu_f(acc[k]);
        }
        __syncthreads();
        {   // phase 3: attn = sigmoid(1x1 conv 32->C); d' = d*attn + d
            float acc[16];
            float bv = b2[c];
            #pragma unroll
            for (int j = 0; j < 16; j++) acc[j] = bv;
            const float* w2r = w2 + c * 32;
            for (int c4i = 0; c4i < 32; c4i++) {
                float w = w2r[c4i];
                float av[16];
                const float4* ap = (const float4*)&a_s[c4i * 36 + lb];
                *(float4*)(av + 0) = ap[0]; *(float4*)(av + 4) = ap[1];
                *(float4*)(av + 8) = ap[2]; *(float4*)(av + 12) = ap[3];
                #pragma unroll
                for (int j = 0; j < 16; j++) acc[j] += w * av[j];
            }
            const float* detb = det_in + ((size_t)b * C_ + c) * L_ + l0 + lb;
            float dv[16];
            #pragma unroll
            for (int j4 = 0; j4 < 4; j4++) *(float4*)(dv + 4 * j4) = *(const float4*)(detb + 4 * j4);
            #pragma unroll
            for (int j = 0; j < 16; j++) {
                float at = sigm_f(acc[j]);
                dpv[j] = dv[j] * at + dv[j];
            }
            float* dob = det_out + ((size_t)b * C_ + c) * L_ + l0 + lb;
            #pragma unroll
            for (int j4 = 0; j4 < 4; j4++) *(float4*)(dob + 4 * j4) = *(const float4*)(dpv + 4 * j4);
        }
    } else {
        const float* detb = det_in + ((size_t)b * C_ + c) * L_ + l0 + lb;
        #pragma unroll
        for (int j4 = 0; j4 < 4; j4++) *(float4*)(dpv + 4 * j4) = *(const float4*)(detb + 4 * j4);
    }

    // phase 4: gate = sigmoid(CxCx3 conv, zero pad); cur_out = cur + gate*d'
    float acc[16];
    float gbv = gb[c];
    #pragma unroll
    for (int j = 0; j < 16; j++) acc[j] = gbv;
    const float* gwr = gw + (size_t)c * C_ * 3;
    for (int ci = 0; ci < C_; ci++) {
        float w0 = gwr[ci * 3 + 0], wv1 = gwr[ci * 3 + 1], wv2 = gwr[ci * 3 + 2];
        float in18[18];
        const float4* rp = (const float4*)&cur_s[ci * 36 + lb];
        *(float4*)(in18 + 0) = rp[0]; *(float4*)(in18 + 4) = rp[1];
        *(float4*)(in18 + 8) = rp[2]; *(float4*)(in18 + 12) = rp[3];
        in18[16] = cur_s[ci * 36 + lb + 16];
        in18[17] = cur_s[ci * 36 + lb + 17];
        #pragma unroll
        for (int j = 0; j < 16; j++) acc[j] += w0 * in18[j] + wv1 * in18[j + 1] + wv2 * in18[j + 2];
    }
    float outv[16];
    #pragma unroll
    for (int j = 0; j < 16; j++) {
        float g = sigm_f(acc[j]);
        outv[j] = cur_s[c * 36 + 1 + lb + j] + g * dpv[j];
    }
    float* cob = cur_out + ((size_t)b * C_ + c) * L_ + l0 + lb;
    #pragma unroll
    for (int j4 = 0; j4 < 4; j4++) *(float4*)(cob + 4 * j4) = *(const float4*)(outv + 4 * j4);
}

extern "C" void kernel_launch(void* const* d_in, const int* in_sizes, int n_in,
                              void* d_out, int out_size, void* d_ws, size_t ws_size,
                              hipStream_t stream) {
    (void)in_sizes; (void)n_in; (void)out_size; (void)ws_size;
    const float* x       = (const float*)d_in[0];
    const float* stat_w  = (const float*)d_in[1];
    const float* stat_b  = (const float*)d_in[2];
    const float* wg1_w   = (const float*)d_in[3];
    const float* wg1_b   = (const float*)d_in[4];
    const float* wg2_w   = (const float*)d_in[5];
    const float* wg2_b   = (const float*)d_in[6];
    const float* gates_w = (const float*)d_in[7];
    const float* gates_b = (const float*)d_in[8];
    const float* a1w     = (const float*)d_in[9];
    const float* a1b     = (const float*)d_in[10];
    const float* a2w     = (const float*)d_in[11];
    const float* a2b     = (const float*)d_in[12];

    float* out = (float*)d_out;
    float* yl  = out;
    float* yh0 = out + BCL;
    float* yh1 = out + 2 * BCL;
    float* yh2 = out + 3 * BCL;
    float* scal = out + 4 * BCL;
    float* lo_all = scal + 2;
    float* hi_all = lo_all + 3 * B_ * FL_;

    float* wsA   = (float*)d_ws;          // 64MB ping buffer
    float* featA = wsA + BCL;
    float* featB = featA + B_ * C_;

    const dim3 cgrid(L_ / 256, C_, B_);
    const dim3 rgrid(L_ / LT, B_);

    // ---- analysis level 0 ----
    mean_kernel<<<dim3(B_ * C_), 256, 0, stream>>>(x, featA);
    mlp_kernel<<<dim3(B_), 1024, 0, stream>>>(featA, stat_w, stat_b, wg1_w, wg1_b, wg2_w, wg2_b,
                                              lo_all, hi_all);
    hipMemsetAsync(featB, 0, B_ * C_ * sizeof(float), stream);
    dwconv_kernel<<<cgrid, 256, 0, stream>>>(x, lo_all, hi_all, wsA, yh0, featB);
    // ---- analysis level 1 ----
    mlp_kernel<<<dim3(B_), 1024, 0, stream>>>(featB, stat_w, stat_b, wg1_w, wg1_b, wg2_w, wg2_b,
                                              lo_all + B_ * FL_, hi_all + B_ * FL_);
    hipMemsetAsync(featA, 0, B_ * C_ * sizeof(float), stream);
    dwconv_kernel<<<cgrid, 256, 0, stream>>>(wsA, lo_all + B_ * FL_, hi_all + B_ * FL_, yl, yh1, featA);
    // ---- analysis level 2 ----
    mlp_kernel<<<dim3(B_), 1024, 0, stream>>>(featA, stat_w, stat_b, wg1_w, wg1_b, wg2_w, wg2_b,
                                              lo_all + 2 * B_ * FL_, hi_all + 2 * B_ * FL_);
    dwconv_kernel<<<cgrid, 256, 0, stream>>>(yl, lo_all + 2 * B_ * FL_, hi_all + 2 * B_ * FL_,
                                             wsA, yh2, nullptr);
    // ---- scalars ----
    ortho_kernel<<<dim3(1), 64, 0, stream>>>(lo_all + 2 * B_ * FL_, scal);
    // ---- reconstruction: i=2 (no attn), i=1, i=0 ----
    recon_kernel<false><<<rgrid, 256, 0, stream>>>(wsA, yh2, nullptr, yl,
        gates_w + 2 * C_ * C_ * 3, gates_b + 2 * C_,
        nullptr, nullptr, nullptr, nullptr);
    recon_kernel<true><<<rgrid, 256, 0, stream>>>(yl, yh1, yh1, wsA,
        gates_w + 1 * C_ * C_ * 3, gates_b + 1 * C_,
        a1w + 32 * C_, a1b + 32, a2w + C_ * 32, a2b + C_);
    recon_kernel<true><<<rgrid, 256, 0, stream>>>(wsA, yh0, yh0, yl,
        gates_w, gates_b, a1w, a1b, a2w, a2b);
}

// Round 2
// 1539.767 us; speedup vs baseline: 1.1023x; 1.1023x over previous
//
#include <hip/hip_runtime.h>

#define B_   32
#define C_   128
#define L_   4096
#define FL_  9
#define DIM_ 512
#define BCL  ((size_t)B_ * C_ * L_)

typedef __attribute__((ext_vector_type(8))) short short8;
typedef __attribute__((ext_vector_type(4))) float f32x4;

__device__ __forceinline__ float gelu_f(float x) {
    return 0.5f * x * (1.0f + erff(x * 0.70710678118654752440f));
}
__device__ __forceinline__ float sigm_f(float x) {
    return 1.0f / (1.0f + expf(-x));
}
__device__ __forceinline__ unsigned short bf16_rne(float x) {
    unsigned int u = __float_as_uint(x);
    u += 0x7fffu + ((u >> 16) & 1u);
    return (unsigned short)(u >> 16);
}
__device__ __forceinline__ float bf16_to_f(unsigned short h) {
    return __uint_as_float(((unsigned int)h) << 16);
}

// ---------------- one-time weight split into bf16 hi/lo, K-major ----------------
// gate: wg[lev][co][k], k = kp*128+ci  (3*128*384)
// attn1: [lev][m][ci] (2*32*128)   attn2: [lev][co][c32] (2*128*32)
__global__ __launch_bounds__(256) void prep_weights(
    const float* __restrict__ gw, const float* __restrict__ a1w, const float* __restrict__ a2w,
    unsigned short* __restrict__ wgh, unsigned short* __restrict__ wgl,
    unsigned short* __restrict__ a1h, unsigned short* __restrict__ a1l,
    unsigned short* __restrict__ a2h, unsigned short* __restrict__ a2l) {
    int i = blockIdx.x * 256 + threadIdx.x;
    float v; unsigned short* ph; unsigned short* pl; int idx;
    if (i < 147456) {
        int lev = i / 49152, r = i % 49152;
        int co = r / 384, k = r % 384, kp = k >> 7, ci = k & 127;
        v = gw[(((size_t)lev * C_ + co) * C_ + ci) * 3 + kp];
        ph = wgh; pl = wgl; idx = i;
    } else if (i < 147456 + 8192) {
        idx = i - 147456;  // a1w is (2,32,128,1) contiguous, same ordering
        v = a1w[idx];
        ph = a1h; pl = a1l;
    } else if (i < 147456 + 16384) {
        idx = i - 147456 - 8192;  // a2w is (2,128,32,1)
        v = a2w[idx];
        ph = a2h; pl = a2l;
    } else return;
    unsigned short h = bf16_rne(v);
    unsigned short l = bf16_rne(v - bf16_to_f(h));
    ph[idx] = h; pl[idx] = l;
}

__device__ __forceinline__ float block_sum_256(float v, float* red) {
    #pragma unroll
    for (int off = 32; off > 0; off >>= 1) v += __shfl_down(v, off);
    const int wv = threadIdx.x >> 6, ln = threadIdx.x & 63;
    if (ln == 0) red[wv] = v;
    __syncthreads();
    return red[0] + red[1] + red[2] + red[3];
}

// ---------------- mean over L (level 0 feat), float4 ----------------
__global__ __launch_bounds__(256) void mean_kernel(const float* __restrict__ in,
                                                   float* __restrict__ feat_sum) {
    __shared__ float red[4];
    const int bc = blockIdx.x, t = threadIdx.x;
    const float4* p = (const float4*)(in + (size_t)bc * L_);
    float v = 0.f;
    #pragma unroll
    for (int it = 0; it < L_ / 1024; it++) {
        float4 x = p[t + 256 * it];
        v += x.x + x.y + x.z + x.w;
    }
    float tot = block_sum_256(v, red);
    if (t == 0) feat_sum[bc] = tot;
}

// ---------------- filter MLP: wave-split-K, coalesced weight reads ----------------
__global__ __launch_bounds__(256) void mlp_kernel(
    const float* __restrict__ feat_sum,
    const float* __restrict__ stat_w, const float* __restrict__ stat_b,
    const float* __restrict__ wg1_w,  const float* __restrict__ wg1_b,
    const float* __restrict__ wg2_w,  const float* __restrict__ wg2_b,
    float* __restrict__ lo_out, float* __restrict__ hi_out) {
    __shared__ float fs[C_];
    __shared__ float h1[DIM_];
    __shared__ float h2[2 * DIM_];
    const int b = blockIdx.x, t = threadIdx.x;
    const int w = t >> 6, lane = t & 63;
    if (t < C_) fs[t] = feat_sum[b * C_ + t] * (1.0f / (float)L_);
    __syncthreads();
    // layer 1: 512 outs, K=128 (2 floats/lane)
    {
        float x0 = fs[2 * lane], x1 = fs[2 * lane + 1];
        #pragma unroll 2
        for (int jj = 0; jj < 128; jj++) {
            int j = 128 * w + jj;
            float2 wv = *(const float2*)&stat_w[(size_t)j * C_ + 2 * lane];
            float p = wv.x * x0 + wv.y * x1;
            #pragma unroll
            for (int off = 32; off > 0; off >>= 1) p += __shfl_xor(p, off);
            if (lane == 0) h1[j] = gelu_f(p + stat_b[j]);
        }
    }
    __syncthreads();
    // layer 2: 1024 outs, K=512 (8 floats/lane)
    {
        float4 x0 = *(const float4*)&h1[8 * lane];
        float4 x1 = *(const float4*)&h1[8 * lane + 4];
        #pragma unroll 2
        for (int jj = 0; jj < 256; jj++) {
            int j = 256 * w + jj;
            const float4 w0 = *(const float4*)&wg1_w[(size_t)j * DIM_ + 8 * lane];
            const float4 w1 = *(const float4*)&wg1_w[(size_t)j * DIM_ + 8 * lane + 4];
            float p = w0.x * x0.x + w0.y * x0.y + w0.z * x0.z + w0.w * x0.w
                    + w1.x * x1.x + w1.y * x1.y + w1.z * x1.z + w1.w * x1.w;
            #pragma unroll
            for (int off = 32; off > 0; off >>= 1) p += __shfl_xor(p, off);
            if (lane == 0) h2[j] = gelu_f(p + wg1_b[j]);
        }
    }
    __syncthreads();
    // layer 3: 18 outs, K=1024 (16 floats/lane)
    for (int j = w; j < 2 * FL_; j += 4) {
        float p = 0.f;
        #pragma unroll
        for (int u = 0; u < 4; u++) {
            float4 wv = *(const float4*)&wg2_w[(size_t)j * (2 * DIM_) + 16 * lane + 4 * u];
            float4 xv = *(const float4*)&h2[16 * lane + 4 * u];
            p += wv.x * xv.x + wv.y * xv.y + wv.z * xv.z + wv.w * xv.w;
        }
        #pragma unroll
        for (int off = 32; off > 0; off >>= 1) p += __shfl_xor(p, off);
        if (lane == 0) {
            p += wg2_b[j];
            if (j < FL_) lo_out[b * FL_ + j] = p;
            else         hi_out[b * FL_ + (j - FL_)] = p;
        }
    }
}

// ---------------- per-sample depthwise 9-tap conv (edge pad), float4, fused feat ----------------
__global__ __launch_bounds__(256) void dwconv_kernel(
    const float* __restrict__ in, const float* __restrict__ lo_f, const float* __restrict__ hi_f,
    float* __restrict__ out_lo, float* __restrict__ out_hi, float* __restrict__ feat_next) {
    __shared__ float s[1032];  // s[j] = in[l0-4+j] edge-clamped
    __shared__ float red[4];
    const int t = threadIdx.x;
    const int l0 = blockIdx.x * 1024;
    const int c = blockIdx.y, b = blockIdx.z;
    const size_t base = ((size_t)b * C_ + c) * L_;
    *(float4*)&s[4 + 4 * t] = *(const float4*)&in[base + l0 + 4 * t];
    if (t < 4) {
        int gl = l0 - 4 + t;
        s[t] = in[base + max(gl, 0)];
    } else if (t < 8) {
        int i = t - 4;
        s[1028 + i] = in[base + min(l0 + 1024 + i, L_ - 1)];
    }
    float lo[FL_], hi[FL_];
    #pragma unroll
    for (int k = 0; k < FL_; k++) { lo[k] = lo_f[b * FL_ + k]; hi[k] = hi_f[b * FL_ + k]; }
    __syncthreads();
    float oL[4] = {0, 0, 0, 0}, oH[4] = {0, 0, 0, 0};
    #pragma unroll
    for (int k = 0; k < FL_; k++) {
        #pragma unroll
        for (int r = 0; r < 4; r++) {
            float v = s[4 * t + r + k];
            oL[r] += lo[k] * v; oH[r] += hi[k] * v;
        }
    }
    *(float4*)&out_lo[base + l0 + 4 * t] = *(float4*)oL;
    *(float4*)&out_hi[base + l0 + 4 * t] = *(float4*)oH;
    if (feat_next) {
        float tot = block_sum_256(oL[0] + oL[1] + oL[2] + oL[3], red);
        if (t == 0) atomicAdd(&feat_next[b * C_ + c], tot);
    }
}

// ---------------- ortho + energy scalars ----------------
__global__ void ortho_kernel(const float* __restrict__ lo2, float* __restrict__ scal) {
    const int t = threadIdx.x;
    float smooth = 0.f, sabs2 = 0.f, amp = 0.f;
    if (t < B_) {
        const float* lo = lo2 + t * FL_;
        float ss = 0.f, sa = 0.f, sm = 0.f, prev = 0.f;
        #pragma unroll
        for (int k = 0; k < FL_; k++) {
            float v = lo[k];
            sm += fabsf(v - prev); prev = v;
            ss += v * v; sa += fabsf(v);
        }
        sm += fabsf(prev);
        float den = sqrtf(ss) + 1e-8f;
        float san = sa / den;
        sabs2 = san * san;
        amp = fabsf(ss / (den * den) - 1.0f);
        smooth = sm;
    }
    #pragma unroll
    for (int off = 32; off > 0; off >>= 1) {
        smooth += __shfl_down(smooth, off);
        sabs2  += __shfl_down(sabs2, off);
        amp    += __shfl_down(amp, off);
    }
    if (t == 0) {
        float lo_smooth = smooth / (float)(B_ * 10);
        float shift = 3.0f * (sabs2 / (float)B_) / 81.0f;
        scal[0] = 0.01f * (shift + amp / (float)B_) + 0.1f * lo_smooth;
        scal[1] = 0.0f;
    }
}

// ---------------- fused reconstruction via split-bf16 MFMA ----------------
// LT=64 per block, 4 waves. Gate conv: M=128(co) x N=64(l) x K=384(kp*128+ci).
// X staged transposed in LDS as bf16 hi/lo planes: X[l][ci], row stride 136 u16.
#define LT   64
#define SX   136
#define SA   40
template <bool HAS_ATTN>
__global__ __launch_bounds__(256, 2) void recon_kernel(
    const float* __restrict__ cur_in, const float* __restrict__ det_in,
    float* __restrict__ det_out, float* __restrict__ cur_out,
    const unsigned short* __restrict__ wgh, const unsigned short* __restrict__ wgl,
    const float* __restrict__ gb,
    const unsigned short* __restrict__ a1h, const unsigned short* __restrict__ a1l,
    const float* __restrict__ b1,
    const unsigned short* __restrict__ a2h, const unsigned short* __restrict__ a2l,
    const float* __restrict__ b2) {
    __shared__ __attribute__((aligned(16))) unsigned short Xh[(LT + 2) * SX];
    __shared__ __attribute__((aligned(16))) unsigned short Xl[(LT + 2) * SX];
    __shared__ __attribute__((aligned(16))) unsigned short aTh[LT * SA];
    __shared__ __attribute__((aligned(16))) unsigned short aTl[LT * SA];

    const int t = threadIdx.x;
    const int b = blockIdx.y;
    const int l0 = blockIdx.x * LT;
    const float* curb = cur_in + (size_t)b * (C_ * L_);

    // ---- stage cur tile -> transposed bf16 hi/lo planes (zero pad at edges) ----
    for (int u = t; u < 64 * (LT + 2); u += 256) {
        int cp = u / (LT + 2), li = u - cp * (LT + 2);
        int gl = l0 - 1 + li;
        float v0 = 0.f, v1 = 0.f;
        if (gl >= 0 && gl < L_) {
            v0 = curb[(size_t)(2 * cp) * L_ + gl];
            v1 = curb[(size_t)(2 * cp + 1) * L_ + gl];
        }
        unsigned short h0 = bf16_rne(v0), h1 = bf16_rne(v1);
        unsigned short e0 = bf16_rne(v0 - bf16_to_f(h0)), e1 = bf16_rne(v1 - bf16_to_f(h1));
        ((unsigned int*)Xh)[li * (SX / 2) + cp] = (unsigned int)h0 | ((unsigned int)h1 << 16);
        ((unsigned int*)Xl)[li * (SX / 2) + cp] = (unsigned int)e0 | ((unsigned int)e1 << 16);
    }
    __syncthreads();

    const int w = t >> 6, ln = t & 15, q = (t >> 4) & 3;

    // ---- gate conv MFMA: wave w -> co rows [32w,32w+32), 2 m-tiles x 4 n-tiles ----
    f32x4 acc[2][4];
    #pragma unroll
    for (int tm = 0; tm < 2; tm++)
        #pragma unroll
        for (int tn = 0; tn < 4; tn++) acc[tm][tn] = (f32x4){0.f, 0.f, 0.f, 0.f};

    #pragma unroll 2
    for (int kk = 0; kk < 12; kk++) {
        const int kp = kk >> 2, ci0 = (kk & 3) * 32;
        short8 ah[2], al[2];
        #pragma unroll
        for (int tm = 0; tm < 2; tm++) {
            int row = 32 * w + 16 * tm + ln;
            ah[tm] = *(const short8*)&wgh[row * 384 + kk * 32 + q * 8];
            al[tm] = *(const short8*)&wgl[row * 384 + kk * 32 + q * 8];
        }
        #pragma unroll
        for (int tn = 0; tn < 4; tn++) {
            int lrow = 16 * tn + ln + kp;
            const short8 bh = *(const short8*)&Xh[lrow * SX + ci0 + q * 8];
            const short8 bl = *(const short8*)&Xl[lrow * SX + ci0 + q * 8];
            #pragma unroll
            for (int tm = 0; tm < 2; tm++) {
                acc[tm][tn] = __builtin_amdgcn_mfma_f32_16x16x32_bf16(ah[tm], bh, acc[tm][tn], 0, 0, 0);
                acc[tm][tn] = __builtin_amdgcn_mfma_f32_16x16x32_bf16(ah[tm], bl, acc[tm][tn], 0, 0, 0);
                acc[tm][tn] = __builtin_amdgcn_mfma_f32_16x16x32_bf16(al[tm], bh, acc[tm][tn], 0, 0, 0);
            }
        }
    }

    // ---- det (+ attn) ----
    f32x4 dpv[2][4];
    #pragma unroll
    for (int tm = 0; tm < 2; tm++)
        #pragma unroll
        for (int tn = 0; tn < 4; tn++) {
            #pragma unroll
            for (int r = 0; r < 4; r++) {
                int co = 32 * w + 16 * tm + 4 * q + r;
                dpv[tm][tn][r] = det_in[((size_t)b * C_ + co) * L_ + l0 + 16 * tn + ln];
            }
        }

    if (HAS_ATTN) {
        // attn1: M=32 x N=16 (wave's own n-tile tn=w) x K=128, center tap
        f32x4 acc1[2];
        acc1[0] = (f32x4){0.f, 0.f, 0.f, 0.f};
        acc1[1] = (f32x4){0.f, 0.f, 0.f, 0.f};
        #pragma unroll
        for (int kc = 0; kc < 4; kc++) {
            int ci0 = kc * 32;
            int lrow = 16 * w + ln + 1;
            const short8 bh = *(const short8*)&Xh[lrow * SX + ci0 + q * 8];
            const short8 bl = *(const short8*)&Xl[lrow * SX + ci0 + q * 8];
            #pragma unroll
            for (int tm = 0; tm < 2; tm++) {
                int row = 16 * tm + ln;
                short8 fh = *(const short8*)&a1h[row * 128 + ci0 + q * 8];
                short8 fl = *(const short8*)&a1l[row * 128 + ci0 + q * 8];
                acc1[tm] = __builtin_amdgcn_mfma_f32_16x16x32_bf16(fh, bh, acc1[tm], 0, 0, 0);
                acc1[tm] = __builtin_amdgcn_mfma_f32_16x16x32_bf16(fh, bl, acc1[tm], 0, 0, 0);
                acc1[tm] = __builtin_amdgcn_mfma_f32_16x16x32_bf16(fl, bh, acc1[tm], 0, 0, 0);
            }
        }
        #pragma unroll
        for (int tm = 0; tm < 2; tm++) {
            #pragma unroll
            for (int r = 0; r < 4; r++) {
                int c32 = 16 * tm + 4 * q + r;
                int lcol = 16 * w + ln;
                float v = gelu_f(acc1[tm][r] + b1[c32]);
                unsigned short h = bf16_rne(v);
                aTh[lcol * SA + c32] = h;
                aTl[lcol * SA + c32] = bf16_rne(v - bf16_to_f(h));
            }
        }
        __syncthreads();
        // attn2: M=128 x N=64 x K=32
        f32x4 acc2[2][4];
        short8 fh2[2], fl2[2];
        #pragma unroll
        for (int tm = 0; tm < 2; tm++) {
            int row = 32 * w + 16 * tm + ln;
            fh2[tm] = *(const short8*)&a2h[row * 32 + q * 8];
            fl2[tm] = *(const short8*)&a2l[row * 32 + q * 8];
            #pragma unroll
            for (int tn = 0; tn < 4; tn++) acc2[tm][tn] = (f32x4){0.f, 0.f, 0.f, 0.f};
        }
        #pragma unroll
        for (int tn = 0; tn < 4; tn++) {
            int lrow = 16 * tn + ln;
            const short8 bh = *(const short8*)&aTh[lrow * SA + q * 8];
            const short8 bl = *(const short8*)&aTl[lrow * SA + q * 8];
            #pragma unroll
            for (int tm = 0; tm < 2; tm++) {
                acc2[tm][tn] = __builtin_amdgcn_mfma_f32_16x16x32_bf16(fh2[tm], bh, acc2[tm][tn], 0, 0, 0);
                acc2[tm][tn] = __builtin_amdgcn_mfma_f32_16x16x32_bf16(fh2[tm], bl, acc2[tm][tn], 0, 0, 0);
                acc2[tm][tn] = __builtin_amdgcn_mfma_f32_16x16x32_bf16(fl2[tm], bh, acc2[tm][tn], 0, 0, 0);
            }
        }
        #pragma unroll
        for (int tm = 0; tm < 2; tm++)
            #pragma unroll
            for (int tn = 0; tn < 4; tn++) {
                #pragma unroll
                for (int r = 0; r < 4; r++) {
                    int co = 32 * w + 16 * tm + 4 * q + r;
                    float at = sigm_f(acc2[tm][tn][r] + b2[co]);
                    float d = dpv[tm][tn][r];
                    d = d * at + d;
                    dpv[tm][tn][r] = d;
                    det_out[((size_t)b * C_ + co) * L_ + l0 + 16 * tn + ln] = d;
                }
            }
    }

    // ---- gate epilogue: cur' = cur + sigmoid(gateacc + gb)*d' ----
    #pragma unroll
    for (int tm = 0; tm < 2; tm++)
        #pragma unroll
        for (int tn = 0; tn < 4; tn++) {
            #pragma unroll
            for (int r = 0; r < 4; r++) {
                int co = 32 * w + 16 * tm + 4 * q + r;
                int lrow = 16 * tn + ln + 1;
                float cur = bf16_to_f(Xh[lrow * SX + co]) + bf16_to_f(Xl[lrow * SX + co]);
                float g = sigm_f(acc[tm][tn][r] + gb[co]);
                cur_out[((size_t)b * C_ + co) * L_ + l0 + 16 * tn + ln] = cur + g * dpv[tm][tn][r];
            }
        }
}

extern "C" void kernel_launch(void* const* d_in, const int* in_sizes, int n_in,
                              void* d_out, int out_size, void* d_ws, size_t ws_size,
                              hipStream_t stream) {
    (void)in_sizes; (void)n_in; (void)out_size; (void)ws_size;
    const float* x       = (const float*)d_in[0];
    const float* stat_w  = (const float*)d_in[1];
    const float* stat_b  = (const float*)d_in[2];
    const float* wg1_w   = (const float*)d_in[3];
    const float* wg1_b   = (const float*)d_in[4];
    const float* wg2_w   = (const float*)d_in[5];
    const float* wg2_b   = (const float*)d_in[6];
    const float* gates_w = (const float*)d_in[7];
    const float* gates_b = (const float*)d_in[8];
    const float* a1w     = (const float*)d_in[9];
    const float* a1b     = (const float*)d_in[10];
    const float* a2w     = (const float*)d_in[11];
    const float* a2b     = (const float*)d_in[12];

    float* out = (float*)d_out;
    float* yl  = out;
    float* yh0 = out + BCL;
    float* yh1 = out + 2 * BCL;
    float* yh2 = out + 3 * BCL;
    float* scal = out + 4 * BCL;
    float* lo_all = scal + 2;
    float* hi_all = lo_all + 3 * B_ * FL_;

    float* wsA   = (float*)d_ws;
    float* featA = wsA + BCL;
    float* featB = featA + B_ * C_ * 4;  // padded slots
    unsigned short* wgh = (unsigned short*)(featB + B_ * C_ * 4);
    unsigned short* wgl = wgh + 147456;
    unsigned short* a1h = wgl + 147456;
    unsigned short* a1l = a1h + 8192;
    unsigned short* a2h = a1l + 8192;
    unsigned short* a2l = a2h + 8192;

    prep_weights<<<dim3((147456 + 16384 + 255) / 256), 256, 0, stream>>>(
        gates_w, a1w, a2w, wgh, wgl, a1h, a1l, a2h, a2l);

    const dim3 cgrid(L_ / 1024, C_, B_);
    const dim3 rgrid(L_ / LT, B_);

    // ---- analysis level 0 ----
    mean_kernel<<<dim3(B_ * C_), 256, 0, stream>>>(x, featA);
    mlp_kernel<<<dim3(B_), 256, 0, stream>>>(featA, stat_w, stat_b, wg1_w, wg1_b, wg2_w, wg2_b,
                                             lo_all, hi_all);
    hipMemsetAsync(featB, 0, B_ * C_ * sizeof(float), stream);
    dwconv_kernel<<<cgrid, 256, 0, stream>>>(x, lo_all, hi_all, wsA, yh0, featB);
    // ---- analysis level 1 ----
    mlp_kernel<<<dim3(B_), 256, 0, stream>>>(featB, stat_w, stat_b, wg1_w, wg1_b, wg2_w, wg2_b,
                                             lo_all + B_ * FL_, hi_all + B_ * FL_);
    hipMemsetAsync(featA, 0, B_ * C_ * sizeof(float), stream);
    dwconv_kernel<<<cgrid, 256, 0, stream>>>(wsA, lo_all + B_ * FL_, hi_all + B_ * FL_, yl, yh1, featA);
    // ---- analysis level 2 ----
    mlp_kernel<<<dim3(B_), 256, 0, stream>>>(featA, stat_w, stat_b, wg1_w, wg1_b, wg2_w, wg2_b,
                                             lo_all + 2 * B_ * FL_, hi_all + 2 * B_ * FL_);
    dwconv_kernel<<<cgrid, 256, 0, stream>>>(yl, lo_all + 2 * B_ * FL_, hi_all + 2 * B_ * FL_,
                                             wsA, yh2, nullptr);
    // ---- scalars ----
    ortho_kernel<<<dim3(1), 64, 0, stream>>>(lo_all + 2 * B_ * FL_, scal);
    // ---- reconstruction: i=2 (no attn), i=1, i=0 ----
    recon_kernel<false><<<rgrid, 256, 0, stream>>>(wsA, yh2, nullptr, yl,
        wgh + 2 * 49152, wgl + 2 * 49152, gates_b + 2 * C_,
        nullptr, nullptr, nullptr, nullptr, nullptr, nullptr);
    recon_kernel<true><<<rgrid, 256, 0, stream>>>(yl, yh1, yh1, wsA,
        wgh + 1 * 49152, wgl + 1 * 49152, gates_b + 1 * C_,
        a1h + 4096, a1l + 4096, a1b + 32,
        a2h + 4096, a2l + 4096, a2b + C_);
    recon_kernel<true><<<rgrid, 256, 0, stream>>>(wsA, yh0, yh0, yl,
        wgh, wgl, gates_b,
        a1h, a1l, a1b,
        a2h, a2l, a2b);
}

// Round 3
// 767.437 us; speedup vs baseline: 2.2116x; 2.0064x over previous
//
#include <hip/hip_runtime.h>

#define B_   32
#define C_   128
#define L_   4096
#define FL_  9
#define DIM_ 512
#define BCL  ((size_t)B_ * C_ * L_)

typedef __attribute__((ext_vector_type(8))) short short8;
typedef __attribute__((ext_vector_type(4))) float f32x4;

__device__ __forceinline__ float gelu_f(float x) {
    return 0.5f * x * (1.0f + erff(x * 0.70710678118654752440f));
}
__device__ __forceinline__ float sigm_f(float x) {
    return 1.0f / (1.0f + expf(-x));
}
__device__ __forceinline__ unsigned short bf16_rne(float x) {
    unsigned int u = __float_as_uint(x);
    u += 0x7fffu + ((u >> 16) & 1u);
    return (unsigned short)(u >> 16);
}
__device__ __forceinline__ float bf16_to_f(unsigned short h) {
    return __uint_as_float(((unsigned int)h) << 16);
}

// ---------------- one-time weight split into bf16 hi/lo, K-major ----------------
__global__ __launch_bounds__(256) void prep_weights(
    const float* __restrict__ gw, const float* __restrict__ a1w, const float* __restrict__ a2w,
    unsigned short* __restrict__ wgh, unsigned short* __restrict__ wgl,
    unsigned short* __restrict__ a1h, unsigned short* __restrict__ a1l,
    unsigned short* __restrict__ a2h, unsigned short* __restrict__ a2l) {
    int i = blockIdx.x * 256 + threadIdx.x;
    float v; unsigned short* ph; unsigned short* pl; int idx;
    if (i < 147456) {
        int lev = i / 49152, r = i % 49152;
        int co = r / 384, k = r % 384, kp = k >> 7, ci = k & 127;
        v = gw[(((size_t)lev * C_ + co) * C_ + ci) * 3 + kp];
        ph = wgh; pl = wgl; idx = i;
    } else if (i < 147456 + 8192) {
        idx = i - 147456;
        v = a1w[idx];
        ph = a1h; pl = a1l;
    } else if (i < 147456 + 16384) {
        idx = i - 147456 - 8192;
        v = a2w[idx];
        ph = a2h; pl = a2l;
    } else return;
    unsigned short h = bf16_rne(v);
    unsigned short l = bf16_rne(v - bf16_to_f(h));
    ph[idx] = h; pl[idx] = l;
}

__device__ __forceinline__ float block_sum_256(float v, float* red) {
    #pragma unroll
    for (int off = 32; off > 0; off >>= 1) v += __shfl_down(v, off);
    const int wv = threadIdx.x >> 6, ln = threadIdx.x & 63;
    if (ln == 0) red[wv] = v;
    __syncthreads();
    return red[0] + red[1] + red[2] + red[3];
}

// ---------------- mean over L (level 0 feat), float4 ----------------
__global__ __launch_bounds__(256) void mean_kernel(const float* __restrict__ in,
                                                   float* __restrict__ feat_sum) {
    __shared__ float red[4];
    const int bc = blockIdx.x, t = threadIdx.x;
    const float4* p = (const float4*)(in + (size_t)bc * L_);
    float v = 0.f;
    #pragma unroll
    for (int it = 0; it < L_ / 1024; it++) {
        float4 x = p[t + 256 * it];
        v += x.x + x.y + x.z + x.w;
    }
    float tot = block_sum_256(v, red);
    if (t == 0) feat_sum[bc] = tot;
}

// ---------------- MLP layer: grid (N/16, samples); wave = 4 outputs, K split over 64 lanes ----
template <int K, int ACT>
__global__ __launch_bounds__(256) void mlp_layer(
    const float* __restrict__ X, const float* __restrict__ W,
    const float* __restrict__ bias, float* __restrict__ Y,
    int N, float xscale) {
    constexpr int PL = K / 64;
    const int w = threadIdx.x >> 6, ln = threadIdx.x & 63;
    const int s = blockIdx.y;
    const int o0 = blockIdx.x * 16 + w * 4;
    float xv[PL];
    const float* xr = X + (size_t)s * K + ln * PL;
    if constexpr (PL == 2) {
        float2 v = *(const float2*)xr;
        xv[0] = v.x * xscale; xv[1] = v.y * xscale;
    } else {
        #pragma unroll
        for (int i = 0; i < PL / 4; i++) {
            float4 v = *(const float4*)(xr + 4 * i);
            xv[4*i] = v.x * xscale; xv[4*i+1] = v.y * xscale;
            xv[4*i+2] = v.z * xscale; xv[4*i+3] = v.w * xscale;
        }
    }
    #pragma unroll
    for (int r = 0; r < 4; r++) {
        int o = o0 + r;
        if (o < N) {
            const float* wr = W + (size_t)o * K + ln * PL;
            float acc = 0.f;
            if constexpr (PL == 2) {
                float2 v = *(const float2*)wr;
                acc = v.x * xv[0] + v.y * xv[1];
            } else {
                #pragma unroll
                for (int i = 0; i < PL / 4; i++) {
                    float4 v = *(const float4*)(wr + 4 * i);
                    acc += v.x * xv[4*i] + v.y * xv[4*i+1] + v.z * xv[4*i+2] + v.w * xv[4*i+3];
                }
            }
            #pragma unroll
            for (int off = 32; off > 0; off >>= 1) acc += __shfl_xor(acc, off);
            if (ln == 0) {
                acc += bias[o];
                Y[(size_t)s * N + o] = ACT ? gelu_f(acc) : acc;
            }
        }
    }
}

// ---------------- MLP final layer: K=1024, 18 outputs split into lo/hi ----------------
__global__ __launch_bounds__(256) void mlp_l3(
    const float* __restrict__ X, const float* __restrict__ W, const float* __restrict__ bias,
    float* __restrict__ lo_out, float* __restrict__ hi_out) {
    constexpr int K = 2 * DIM_, PL = K / 64;
    const int w = threadIdx.x >> 6, ln = threadIdx.x & 63;
    const int s = blockIdx.y;
    const int o0 = blockIdx.x * 16 + w * 4;
    float xv[PL];
    const float* xr = X + (size_t)s * K + ln * PL;
    #pragma unroll
    for (int i = 0; i < PL / 4; i++) {
        float4 v = *(const float4*)(xr + 4 * i);
        xv[4*i] = v.x; xv[4*i+1] = v.y; xv[4*i+2] = v.z; xv[4*i+3] = v.w;
    }
    #pragma unroll
    for (int r = 0; r < 4; r++) {
        int o = o0 + r;
        if (o < 2 * FL_) {
            const float* wr = W + (size_t)o * K + ln * PL;
            float acc = 0.f;
            #pragma unroll
            for (int i = 0; i < PL / 4; i++) {
                float4 v = *(const float4*)(wr + 4 * i);
                acc += v.x * xv[4*i] + v.y * xv[4*i+1] + v.z * xv[4*i+2] + v.w * xv[4*i+3];
            }
            #pragma unroll
            for (int off = 32; off > 0; off >>= 1) acc += __shfl_xor(acc, off);
            if (ln == 0) {
                acc += bias[o];
                if (o < FL_) lo_out[s * FL_ + o] = acc;
                else         hi_out[s * FL_ + (o - FL_)] = acc;
            }
        }
    }
}

// ---------------- per-sample depthwise 9-tap conv (edge pad), float4, fused feat ----------------
__global__ __launch_bounds__(256) void dwconv_kernel(
    const float* __restrict__ in, const float* __restrict__ lo_f, const float* __restrict__ hi_f,
    float* __restrict__ out_lo, float* __restrict__ out_hi, float* __restrict__ feat_next) {
    __shared__ float s[1032];
    __shared__ float red[4];
    const int t = threadIdx.x;
    const int l0 = blockIdx.x * 1024;
    const int c = blockIdx.y, b = blockIdx.z;
    const size_t base = ((size_t)b * C_ + c) * L_;
    *(float4*)&s[4 + 4 * t] = *(const float4*)&in[base + l0 + 4 * t];
    if (t < 4) {
        int gl = l0 - 4 + t;
        s[t] = in[base + max(gl, 0)];
    } else if (t < 8) {
        int i = t - 4;
        s[1028 + i] = in[base + min(l0 + 1024 + i, L_ - 1)];
    }
    float lo[FL_], hi[FL_];
    #pragma unroll
    for (int k = 0; k < FL_; k++) { lo[k] = lo_f[b * FL_ + k]; hi[k] = hi_f[b * FL_ + k]; }
    __syncthreads();
    float oL[4] = {0, 0, 0, 0}, oH[4] = {0, 0, 0, 0};
    #pragma unroll
    for (int k = 0; k < FL_; k++) {
        #pragma unroll
        for (int r = 0; r < 4; r++) {
            float v = s[4 * t + r + k];
            oL[r] += lo[k] * v; oH[r] += hi[k] * v;
        }
    }
    *(float4*)&out_lo[base + l0 + 4 * t] = *(float4*)oL;
    *(float4*)&out_hi[base + l0 + 4 * t] = *(float4*)oH;
    if (feat_next) {
        float tot = block_sum_256(oL[0] + oL[1] + oL[2] + oL[3], red);
        if (t == 0) atomicAdd(&feat_next[b * C_ + c], tot);
    }
}

// ---------------- ortho + energy scalars ----------------
__global__ void ortho_kernel(const float* __restrict__ lo2, float* __restrict__ scal) {
    const int t = threadIdx.x;
    float smooth = 0.f, sabs2 = 0.f, amp = 0.f;
    if (t < B_) {
        const float* lo = lo2 + t * FL_;
        float ss = 0.f, sa = 0.f, sm = 0.f, prev = 0.f;
        #pragma unroll
        for (int k = 0; k < FL_; k++) {
            float v = lo[k];
            sm += fabsf(v - prev); prev = v;
            ss += v * v; sa += fabsf(v);
        }
        sm += fabsf(prev);
        float den = sqrtf(ss) + 1e-8f;
        float san = sa / den;
        sabs2 = san * san;
        amp = fabsf(ss / (den * den) - 1.0f);
        smooth = sm;
    }
    #pragma unroll
    for (int off = 32; off > 0; off >>= 1) {
        smooth += __shfl_down(smooth, off);
        sabs2  += __shfl_down(sabs2, off);
        amp    += __shfl_down(amp, off);
    }
    if (t == 0) {
        float lo_smooth = smooth / (float)(B_ * 10);
        float shift = 3.0f * (sabs2 / (float)B_) / 81.0f;
        scal[0] = 0.01f * (shift + amp / (float)B_) + 0.1f * lo_smooth;
        scal[1] = 0.0f;
    }
}

// ---------------- fused reconstruction via split-bf16 MFMA ----------------
#define LT   64
#define SX   136
#define SA   40
template <bool HAS_ATTN>
__global__ __launch_bounds__(256, 2) void recon_kernel(
    const float* __restrict__ cur_in, const float* __restrict__ det_in,
    float* __restrict__ det_out, float* __restrict__ cur_out,
    const unsigned short* __restrict__ wgh, const unsigned short* __restrict__ wgl,
    const float* __restrict__ gb,
    const unsigned short* __restrict__ a1h, const unsigned short* __restrict__ a1l,
    const float* __restrict__ b1,
    const unsigned short* __restrict__ a2h, const unsigned short* __restrict__ a2l,
    const float* __restrict__ b2) {
    __shared__ __attribute__((aligned(16))) unsigned short Xh[(LT + 2) * SX];
    __shared__ __attribute__((aligned(16))) unsigned short Xl[(LT + 2) * SX];
    __shared__ __attribute__((aligned(16))) unsigned short aTh[LT * SA];
    __shared__ __attribute__((aligned(16))) unsigned short aTl[LT * SA];

    const int t = threadIdx.x;
    const int b = blockIdx.y;
    const int l0 = blockIdx.x * LT;
    const float* curb = cur_in + (size_t)b * (C_ * L_);

    for (int u = t; u < 64 * (LT + 2); u += 256) {
        int cp = u / (LT + 2), li = u - cp * (LT + 2);
        int gl = l0 - 1 + li;
        float v0 = 0.f, v1 = 0.f;
        if (gl >= 0 && gl < L_) {
            v0 = curb[(size_t)(2 * cp) * L_ + gl];
            v1 = curb[(size_t)(2 * cp + 1) * L_ + gl];
        }
        unsigned short h0 = bf16_rne(v0), h1 = bf16_rne(v1);
        unsigned short e0 = bf16_rne(v0 - bf16_to_f(h0)), e1 = bf16_rne(v1 - bf16_to_f(h1));
        ((unsigned int*)Xh)[li * (SX / 2) + cp] = (unsigned int)h0 | ((unsigned int)h1 << 16);
        ((unsigned int*)Xl)[li * (SX / 2) + cp] = (unsigned int)e0 | ((unsigned int)e1 << 16);
    }
    __syncthreads();

    const int w = t >> 6, ln = t & 15, q = (t >> 4) & 3;

    f32x4 acc[2][4];
    #pragma unroll
    for (int tm = 0; tm < 2; tm++)
        #pragma unroll
        for (int tn = 0; tn < 4; tn++) acc[tm][tn] = (f32x4){0.f, 0.f, 0.f, 0.f};

    #pragma unroll 2
    for (int kk = 0; kk < 12; kk++) {
        const int kp = kk >> 2, ci0 = (kk & 3) * 32;
        short8 ah[2], al[2];
        #pragma unroll
        for (int tm = 0; tm < 2; tm++) {
            int row = 32 * w + 16 * tm + ln;
            ah[tm] = *(const short8*)&wgh[row * 384 + kk * 32 + q * 8];
            al[tm] = *(const short8*)&wgl[row * 384 + kk * 32 + q * 8];
        }
        #pragma unroll
        for (int tn = 0; tn < 4; tn++) {
            int lrow = 16 * tn + ln + kp;
            const short8 bh = *(const short8*)&Xh[lrow * SX + ci0 + q * 8];
            const short8 bl = *(const short8*)&Xl[lrow * SX + ci0 + q * 8];
            #pragma unroll
            for (int tm = 0; tm < 2; tm++) {
                acc[tm][tn] = __builtin_amdgcn_mfma_f32_16x16x32_bf16(ah[tm], bh, acc[tm][tn], 0, 0, 0);
                acc[tm][tn] = __builtin_amdgcn_mfma_f32_16x16x32_bf16(ah[tm], bl, acc[tm][tn], 0, 0, 0);
                acc[tm][tn] = __builtin_amdgcn_mfma_f32_16x16x32_bf16(al[tm], bh, acc[tm][tn], 0, 0, 0);
            }
        }
    }

    f32x4 dpv[2][4];
    #pragma unroll
    for (int tm = 0; tm < 2; tm++)
        #pragma unroll
        for (int tn = 0; tn < 4; tn++) {
            #pragma unroll
            for (int r = 0; r < 4; r++) {
                int co = 32 * w + 16 * tm + 4 * q + r;
                dpv[tm][tn][r] = det_in[((size_t)b * C_ + co) * L_ + l0 + 16 * tn + ln];
            }
        }

    if (HAS_ATTN) {
        f32x4 acc1[2];
        acc1[0] = (f32x4){0.f, 0.f, 0.f, 0.f};
        acc1[1] = (f32x4){0.f, 0.f, 0.f, 0.f};
        #pragma unroll
        for (int kc = 0; kc < 4; kc++) {
            int ci0 = kc * 32;
            int lrow = 16 * w + ln + 1;
            const short8 bh = *(const short8*)&Xh[lrow * SX + ci0 + q * 8];
            const short8 bl = *(const short8*)&Xl[lrow * SX + ci0 + q * 8];
            #pragma unroll
            for (int tm = 0; tm < 2; tm++) {
                int row = 16 * tm + ln;
                short8 fh = *(const short8*)&a1h[row * 128 + ci0 + q * 8];
                short8 fl = *(const short8*)&a1l[row * 128 + ci0 + q * 8];
                acc1[tm] = __builtin_amdgcn_mfma_f32_16x16x32_bf16(fh, bh, acc1[tm], 0, 0, 0);
                acc1[tm] = __builtin_amdgcn_mfma_f32_16x16x32_bf16(fh, bl, acc1[tm], 0, 0, 0);
                acc1[tm] = __builtin_amdgcn_mfma_f32_16x16x32_bf16(fl, bh, acc1[tm], 0, 0, 0);
            }
        }
        #pragma unroll
        for (int tm = 0; tm < 2; tm++) {
            #pragma unroll
            for (int r = 0; r < 4; r++) {
                int c32 = 16 * tm + 4 * q + r;
                int lcol = 16 * w + ln;
                float v = gelu_f(acc1[tm][r] + b1[c32]);
                unsigned short h = bf16_rne(v);
                aTh[lcol * SA + c32] = h;
                aTl[lcol * SA + c32] = bf16_rne(v - bf16_to_f(h));
            }
        }
        __syncthreads();
        f32x4 acc2[2][4];
        short8 fh2[2], fl2[2];
        #pragma unroll
        for (int tm = 0; tm < 2; tm++) {
            int row = 32 * w + 16 * tm + ln;
            fh2[tm] = *(const short8*)&a2h[row * 32 + q * 8];
            fl2[tm] = *(const short8*)&a2l[row * 32 + q * 8];
            #pragma unroll
            for (int tn = 0; tn < 4; tn++) acc2[tm][tn] = (f32x4){0.f, 0.f, 0.f, 0.f};
        }
        #pragma unroll
        for (int tn = 0; tn < 4; tn++) {
            int lrow = 16 * tn + ln;
            const short8 bh = *(const short8*)&aTh[lrow * SA + q * 8];
            const short8 bl = *(const short8*)&aTl[lrow * SA + q * 8];
            #pragma unroll
            for (int tm = 0; tm < 2; tm++) {
                acc2[tm][tn] = __builtin_amdgcn_mfma_f32_16x16x32_bf16(fh2[tm], bh, acc2[tm][tn], 0, 0, 0);
                acc2[tm][tn] = __builtin_amdgcn_mfma_f32_16x16x32_bf16(fh2[tm], bl, acc2[tm][tn], 0, 0, 0);
                acc2[tm][tn] = __builtin_amdgcn_mfma_f32_16x16x32_bf16(fl2[tm], bh, acc2[tm][tn], 0, 0, 0);
            }
        }
        #pragma unroll
        for (int tm = 0; tm < 2; tm++)
            #pragma unroll
            for (int tn = 0; tn < 4; tn++) {
                #pragma unroll
                for (int r = 0; r < 4; r++) {
                    int co = 32 * w + 16 * tm + 4 * q + r;
                    float at = sigm_f(acc2[tm][tn][r] + b2[co]);
                    float d = dpv[tm][tn][r];
                    d = d * at + d;
                    dpv[tm][tn][r] = d;
                    det_out[((size_t)b * C_ + co) * L_ + l0 + 16 * tn + ln] = d;
                }
            }
    }

    #pragma unroll
    for (int tm = 0; tm < 2; tm++)
        #pragma unroll
        for (int tn = 0; tn < 4; tn++) {
            #pragma unroll
            for (int r = 0; r < 4; r++) {
                int co = 32 * w + 16 * tm + 4 * q + r;
                int lrow = 16 * tn + ln + 1;
                float cur = bf16_to_f(Xh[lrow * SX + co]) + bf16_to_f(Xl[lrow * SX + co]);
                float g = sigm_f(acc[tm][tn][r] + gb[co]);
                cur_out[((size_t)b * C_ + co) * L_ + l0 + 16 * tn + ln] = cur + g * dpv[tm][tn][r];
            }
        }
}

static inline void run_mlp(const float* feat, const float* stat_w, const float* stat_b,
                           const float* wg1_w, const float* wg1_b,
                           const float* wg2_w, const float* wg2_b,
                           float* h1_g, float* h2_g, float* lo_out, float* hi_out,
                           hipStream_t stream) {
    mlp_layer<C_, 1><<<dim3(DIM_ / 16, B_), 256, 0, stream>>>(
        feat, stat_w, stat_b, h1_g, DIM_, 1.0f / (float)L_);
    mlp_layer<DIM_, 1><<<dim3(2 * DIM_ / 16, B_), 256, 0, stream>>>(
        h1_g, wg1_w, wg1_b, h2_g, 2 * DIM_, 1.0f);
    mlp_l3<<<dim3(2, B_), 256, 0, stream>>>(h2_g, wg2_w, wg2_b, lo_out, hi_out);
}

extern "C" void kernel_launch(void* const* d_in, const int* in_sizes, int n_in,
                              void* d_out, int out_size, void* d_ws, size_t ws_size,
                              hipStream_t stream) {
    (void)in_sizes; (void)n_in; (void)out_size; (void)ws_size;
    const float* x       = (const float*)d_in[0];
    const float* stat_w  = (const float*)d_in[1];
    const float* stat_b  = (const float*)d_in[2];
    const float* wg1_w   = (const float*)d_in[3];
    const float* wg1_b   = (const float*)d_in[4];
    const float* wg2_w   = (const float*)d_in[5];
    const float* wg2_b   = (const float*)d_in[6];
    const float* gates_w = (const float*)d_in[7];
    const float* gates_b = (const float*)d_in[8];
    const float* a1w     = (const float*)d_in[9];
    const float* a1b     = (const float*)d_in[10];
    const float* a2w     = (const float*)d_in[11];
    const float* a2b     = (const float*)d_in[12];

    float* out = (float*)d_out;
    float* yl  = out;
    float* yh0 = out + BCL;
    float* yh1 = out + 2 * BCL;
    float* yh2 = out + 3 * BCL;
    float* scal = out + 4 * BCL;
    float* lo_all = scal + 2;
    float* hi_all = lo_all + 3 * B_ * FL_;

    float* wsA   = (float*)d_ws;
    float* featA = wsA + BCL;
    float* featB = featA + B_ * C_;
    float* h1_g  = featB + B_ * C_;
    float* h2_g  = h1_g + B_ * DIM_;
    unsigned short* wgh = (unsigned short*)(h2_g + B_ * 2 * DIM_);
    unsigned short* wgl = wgh + 147456;
    unsigned short* a1h = wgl + 147456;
    unsigned short* a1l = a1h + 8192;
    unsigned short* a2h = a1l + 8192;
    unsigned short* a2l = a2h + 8192;

    prep_weights<<<dim3((147456 + 16384 + 255) / 256), 256, 0, stream>>>(
        gates_w, a1w, a2w, wgh, wgl, a1h, a1l, a2h, a2l);

    const dim3 cgrid(L_ / 1024, C_, B_);
    const dim3 rgrid(L_ / LT, B_);

    // ---- analysis level 0 ----
    mean_kernel<<<dim3(B_ * C_), 256, 0, stream>>>(x, featA);
    run_mlp(featA, stat_w, stat_b, wg1_w, wg1_b, wg2_w, wg2_b, h1_g, h2_g,
            lo_all, hi_all, stream);
    hipMemsetAsync(featB, 0, B_ * C_ * sizeof(float), stream);
    dwconv_kernel<<<cgrid, 256, 0, stream>>>(x, lo_all, hi_all, wsA, yh0, featB);
    // ---- analysis level 1 ----
    run_mlp(featB, stat_w, stat_b, wg1_w, wg1_b, wg2_w, wg2_b, h1_g, h2_g,
            lo_all + B_ * FL_, hi_all + B_ * FL_, stream);
    hipMemsetAsync(featA, 0, B_ * C_ * sizeof(float), stream);
    dwconv_kernel<<<cgrid, 256, 0, stream>>>(wsA, lo_all + B_ * FL_, hi_all + B_ * FL_, yl, yh1, featA);
    // ---- analysis level 2 ----
    run_mlp(featA, stat_w, stat_b, wg1_w, wg1_b, wg2_w, wg2_b, h1_g, h2_g,
            lo_all + 2 * B_ * FL_, hi_all + 2 * B_ * FL_, stream);
    dwconv_kernel<<<cgrid, 256, 0, stream>>>(yl, lo_all + 2 * B_ * FL_, hi_all + 2 * B_ * FL_,
                                             wsA, yh2, nullptr);
    // ---- scalars ----
    ortho_kernel<<<dim3(1), 64, 0, stream>>>(lo_all + 2 * B_ * FL_, scal);
    // ---- reconstruction: i=2 (no attn), i=1, i=0 ----
    recon_kernel<false><<<rgrid, 256, 0, stream>>>(wsA, yh2, nullptr, yl,
        wgh + 2 * 49152, wgl + 2 * 49152, gates_b + 2 * C_,
        nullptr, nullptr, nullptr, nullptr, nullptr, nullptr);
    recon_kernel<true><<<rgrid, 256, 0, stream>>>(yl, yh1, yh1, wsA,
        wgh + 1 * 49152, wgl + 1 * 49152, gates_b + 1 * C_,
        a1h + 4096, a1l + 4096, a1b + 32,
        a2h + 4096, a2l + 4096, a2b + C_);
    recon_kernel<true><<<rgrid, 256, 0, stream>>>(wsA, yh0, yh0, yl,
        wgh, wgl, gates_b,
        a1h, a1l, a1b,
        a2h, a2l, a2b);
}